// Round 3
// baseline (588.350 us; speedup 1.0000x reference)
//
#include <hip/hip_runtime.h>
#include <hip/hip_bf16.h>

#define N_NODES 100000
#define N_EDGES 1600000
#define D_IN    128
#define D_HID   16
#define D_OUT   32

#define BUCKET_SHIFT 6
#define BUCKET_NODES 64                         // nodes per bucket
#define NB 1563                                 // ceil(100000/64)

// ---------------------------------------------------------------------------
// Histogram of dst-buckets. 391 blocks x 4096 edges, LDS pre-aggregation.
// ---------------------------------------------------------------------------
__global__ __launch_bounds__(256) void k_hist(const int* __restrict__ dst,
                                              int* __restrict__ counts) {
    __shared__ int h[NB];
    for (int i = threadIdx.x; i < NB; i += 256) h[i] = 0;
    __syncthreads();
    int base = blockIdx.x * 4096;
#pragma unroll
    for (int it = 0; it < 16; ++it) {
        int e = base + it * 256 + threadIdx.x;
        if (e < N_EDGES) atomicAdd(&h[dst[e] >> BUCKET_SHIFT], 1);
    }
    __syncthreads();
    for (int i = threadIdx.x; i < NB; i += 256) {
        int c = h[i];
        if (c) atomicAdd(&counts[i], c);
    }
}

// ---------------------------------------------------------------------------
// Exclusive scan of NB bucket counts (single 1024-thread block, 2 elems/thr).
// Produces offsets[NB+1] and the mutable cursor copy.
// ---------------------------------------------------------------------------
__global__ __launch_bounds__(1024) void k_scan(const int* __restrict__ counts,
                                               int* __restrict__ offsets,
                                               int* __restrict__ cursor) {
    __shared__ int t[1024];
    int tid = threadIdx.x;
    int i0 = 2 * tid, i1 = 2 * tid + 1;
    int v0 = (i0 < NB) ? counts[i0] : 0;
    int v1 = (i1 < NB) ? counts[i1] : 0;
    int sum = v0 + v1;
    t[tid] = sum;
    __syncthreads();
#pragma unroll
    for (int off = 1; off < 1024; off <<= 1) {
        int x = (tid >= off) ? t[tid - off] : 0;
        __syncthreads();
        t[tid] += x;
        __syncthreads();
    }
    int excl = t[tid] - sum;
    if (i0 < NB) { offsets[i0] = excl;      cursor[i0] = excl;      }
    if (i1 < NB) { offsets[i1] = excl + v0; cursor[i1] = excl + v0; }
    if (tid == 0) offsets[NB] = N_EDGES;
}

// ---------------------------------------------------------------------------
// Bucket-grouping scatter: pairs[slot] = (src << 6) | (dst & 63), grouped by
// dst-bucket. Only 1563 active write frontiers -> L2-merged full-line writes.
// ---------------------------------------------------------------------------
__global__ __launch_bounds__(256) void k_scatter_pairs(const int* __restrict__ src,
                                                       const int* __restrict__ dst,
                                                       int* __restrict__ cursor,
                                                       int* __restrict__ pairs) {
    int e = blockIdx.x * 256 + threadIdx.x;
    if (e >= N_EDGES) return;
    int d = dst[e];
    int v = (src[e] << BUCKET_SHIFT) | (d & (BUCKET_NODES - 1));
    int p = atomicAdd(&cursor[d >> BUCKET_SHIFT], 1);
    pairs[p] = v;
}

// ---------------------------------------------------------------------------
// Y = feat @ W1 -> bf16.  Thread per node, float4 row loads, W1 in LDS.
// ---------------------------------------------------------------------------
__global__ __launch_bounds__(256) void k_mm1(const float* __restrict__ feat,
                                             const float* __restrict__ W1,
                                             __hip_bfloat16* __restrict__ Y) {
    __shared__ float sW[D_IN * D_HID];  // 8 KB
    for (int i = threadIdx.x; i < D_IN * D_HID; i += 256)
        sW[i] = W1[i];
    __syncthreads();

    int n = blockIdx.x * 256 + threadIdx.x;
    if (n >= N_NODES) return;

    const float4* f4 = (const float4*)(feat + (size_t)n * D_IN);
    const float4* sW4 = (const float4*)sW;

    float4 acc[4];
#pragma unroll
    for (int q = 0; q < 4; ++q) acc[q] = make_float4(0.f, 0.f, 0.f, 0.f);

#pragma unroll 8
    for (int kq = 0; kq < 32; ++kq) {
        float4 f = f4[kq];
        int k0 = kq * 4;
#pragma unroll
        for (int jq = 0; jq < 4; ++jq) {
            float4 w0 = sW4[(k0 + 0) * 4 + jq];
            float4 w1 = sW4[(k0 + 1) * 4 + jq];
            float4 w2 = sW4[(k0 + 2) * 4 + jq];
            float4 w3 = sW4[(k0 + 3) * 4 + jq];
            acc[jq].x += f.x * w0.x + f.y * w1.x + f.z * w2.x + f.w * w3.x;
            acc[jq].y += f.x * w0.y + f.y * w1.y + f.z * w2.y + f.w * w3.y;
            acc[jq].z += f.x * w0.z + f.y * w1.z + f.z * w2.z + f.w * w3.z;
            acc[jq].w += f.x * w0.w + f.y * w1.w + f.z * w2.w + f.w * w3.w;
        }
    }
    union { __hip_bfloat16 h[16]; uint4 v[2]; } u;
#pragma unroll
    for (int q = 0; q < 4; ++q) {
        u.h[q * 4 + 0] = __float2bfloat16(acc[q].x);
        u.h[q * 4 + 1] = __float2bfloat16(acc[q].y);
        u.h[q * 4 + 2] = __float2bfloat16(acc[q].z);
        u.h[q * 4 + 3] = __float2bfloat16(acc[q].w);
    }
    uint4* y = (uint4*)(Y + (size_t)n * D_HID);
    y[0] = u.v[0];
    y[1] = u.v[1];
}

// ---------------------------------------------------------------------------
// Layer-1 aggregation, one workgroup per bucket. LDS fp32 accumulate, fused
// bias+ReLU epilogue, bf16 output H1.
// ---------------------------------------------------------------------------
__global__ __launch_bounds__(256) void k_agg1(const int* __restrict__ offsets,
                                              const int* __restrict__ pairs,
                                              const __hip_bfloat16* __restrict__ Y,
                                              const float* __restrict__ b1,
                                              __hip_bfloat16* __restrict__ H1) {
    __shared__ float acc[BUCKET_NODES * D_HID];  // 4 KB
    int tid = threadIdx.x;
    for (int i = tid; i < BUCKET_NODES * D_HID; i += 256) acc[i] = 0.f;
    __syncthreads();

    int b = blockIdx.x;
    int beg = offsets[b], end = offsets[b + 1];
    int g = tid >> 4, j = tid & 15;
    for (int i = beg + g; i < end; i += 16) {
        int v = pairs[i];
        int s = v >> BUCKET_SHIFT;
        int ln = v & (BUCKET_NODES - 1);
        atomicAdd(&acc[ln * D_HID + j], __bfloat162float(Y[(size_t)s * D_HID + j]));
    }
    __syncthreads();

    int nodebase = b * BUCKET_NODES;
    for (int t = tid; t < BUCKET_NODES * D_HID; t += 256) {
        int n = t >> 4, jj = t & 15;
        int node = nodebase + n;
        if (node < N_NODES) {
            float h = acc[t] + b1[jj];
            H1[(size_t)node * D_HID + jj] = __float2bfloat16(h > 0.f ? h : 0.f);
        }
    }
}

// ---------------------------------------------------------------------------
// Layer-2 aggregation + fused mm2 epilogue: out = agg2 @ W2 + b2.
// ---------------------------------------------------------------------------
__global__ __launch_bounds__(256) void k_agg2(const int* __restrict__ offsets,
                                              const int* __restrict__ pairs,
                                              const __hip_bfloat16* __restrict__ H1,
                                              const float* __restrict__ W2,
                                              const float* __restrict__ b2,
                                              float* __restrict__ out) {
    __shared__ float acc[BUCKET_NODES * D_HID];  // 4 KB
    __shared__ float sW2[D_HID * D_OUT];         // 2 KB
    __shared__ float sb2[D_OUT];
    int tid = threadIdx.x;
    for (int i = tid; i < BUCKET_NODES * D_HID; i += 256) acc[i] = 0.f;
    for (int i = tid; i < D_HID * D_OUT; i += 256) sW2[i] = W2[i];
    if (tid < D_OUT) sb2[tid] = b2[tid];
    __syncthreads();

    int b = blockIdx.x;
    int beg = offsets[b], end = offsets[b + 1];
    int g = tid >> 4, j = tid & 15;
    for (int i = beg + g; i < end; i += 16) {
        int v = pairs[i];
        int s = v >> BUCKET_SHIFT;
        int ln = v & (BUCKET_NODES - 1);
        atomicAdd(&acc[ln * D_HID + j], __bfloat162float(H1[(size_t)s * D_HID + j]));
    }
    __syncthreads();

    int nodebase = b * BUCKET_NODES;
    for (int t = tid; t < BUCKET_NODES * D_OUT; t += 256) {
        int n = t >> 5, o = t & 31;
        int node = nodebase + n;
        if (node < N_NODES) {
            float a = sb2[o];
#pragma unroll
            for (int jj = 0; jj < D_HID; ++jj)
                a = fmaf(acc[n * D_HID + jj], sW2[jj * D_OUT + o], a);
            out[(size_t)node * D_OUT + o] = a;
        }
    }
}

// ---------------------------------------------------------------------------
extern "C" void kernel_launch(void* const* d_in, const int* in_sizes, int n_in,
                              void* d_out, int out_size, void* d_ws, size_t ws_size,
                              hipStream_t stream) {
    const float* feat = (const float*)d_in[0];
    const int*   src  = (const int*)d_in[1];
    const int*   dst  = (const int*)d_in[2];
    const float* W1   = (const float*)d_in[3];
    const float* b1   = (const float*)d_in[4];
    const float* W2   = (const float*)d_in[5];
    const float* b2   = (const float*)d_in[6];
    float* out = (float*)d_out;

    // ws layout (< 13 MB of the proven 19.2 MB):
    //   [0      , 6.4M )  pairs   (int, 1.6M)  — bucket-grouped packed edges
    //   [6.4M   , 9.6M )  Y       (bf16, 100000 x 16)
    //   [9.6M   , 12.8M)  H1      (bf16, 100000 x 16)
    //   [12.8M  , ...  )  counts / offsets / cursor (each < 8 KB)
    char* base = (char*)d_ws;
    int*            pairs   = (int*)(base);
    __hip_bfloat16* Y       = (__hip_bfloat16*)(base + 6400000);
    __hip_bfloat16* H1      = (__hip_bfloat16*)(base + 9600000);
    int*            counts  = (int*)(base + 12800000);
    int*            offsets = (int*)(base + 12800000 + 8192);
    int*            cursor  = (int*)(base + 12800000 + 16384);

    hipMemsetAsync(counts, 0, NB * sizeof(int), stream);

    // CSR-by-bucket build
    k_hist         <<<391, 256, 0, stream>>>(dst, counts);
    k_scan         <<<1, 1024, 0, stream>>>(counts, offsets, cursor);
    k_scatter_pairs<<<N_EDGES / 256, 256, 0, stream>>>(src, dst, cursor, pairs);

    // layer 1: project (cheap order) then bucket-aggregate with fused ReLU
    k_mm1 <<<(N_NODES + 255) / 256, 256, 0, stream>>>(feat, W1, Y);
    k_agg1<<<NB, 256, 0, stream>>>(offsets, pairs, Y, b1, H1);

    // layer 2: bucket-aggregate with fused mm2 epilogue
    k_agg2<<<NB, 256, 0, stream>>>(offsets, pairs, H1, W2, b2, out);
}

// Round 4
// 415.465 us; speedup vs baseline: 1.4161x; 1.4161x over previous
//
#include <hip/hip_runtime.h>
#include <hip/hip_bf16.h>

#define N_NODES 100000
#define N_EDGES 1600000
#define D_IN    128
#define D_HID   16
#define D_OUT   32

#define BSHIFT 7
#define BNODES 128                 // nodes per bucket
#define NB 782                     // ceil(100000/128)
#define NBPAD 1024                 // scan padding (256 threads x 4)
#define SCHUNK 4096                // edges per sort block
#define SBLOCKS 391                // ceil(1600000/4096)

// bf16x2 helpers -------------------------------------------------------------
__device__ inline float bf_lo(unsigned dw) {
    return __uint_as_float(dw << 16);
}
__device__ inline float bf_hi(unsigned dw) {
    return __uint_as_float(dw & 0xffff0000u);
}
__device__ inline unsigned bf_pack(float f0, float f1) {
    union { __hip_bfloat16 h[2]; unsigned u; } pu;
    pu.h[0] = __float2bfloat16(f0);
    pu.h[1] = __float2bfloat16(f1);
    return pu.u;
}

// ---------------------------------------------------------------------------
// Histogram of dst buckets (LDS pre-aggregation, then global atomics).
// ---------------------------------------------------------------------------
__global__ __launch_bounds__(256) void k_hist(const int* __restrict__ dst,
                                              int* __restrict__ counts) {
    __shared__ int h[NB];
    int tid = threadIdx.x;
    for (int i = tid; i < NB; i += 256) h[i] = 0;
    __syncthreads();
    int base = blockIdx.x * SCHUNK;
#pragma unroll
    for (int k = 0; k < 16; ++k) {
        int e = base + k * 256 + tid;
        if (e < N_EDGES) atomicAdd(&h[dst[e] >> BSHIFT], 1);
    }
    __syncthreads();
    for (int i = tid; i < NB; i += 256) {
        int c = h[i];
        if (c) atomicAdd(&counts[i], c);
    }
}

// ---------------------------------------------------------------------------
// Exclusive scan of NB counts -> offsets[NB+1] and mutable cursor copy.
// ---------------------------------------------------------------------------
__global__ __launch_bounds__(256) void k_scan(const int* __restrict__ counts,
                                              int* __restrict__ offsets,
                                              int* __restrict__ cursor) {
    __shared__ int t[256];
    int tid = threadIdx.x;
    int i0 = tid * 4;
    int v0 = (i0 + 0 < NB) ? counts[i0 + 0] : 0;
    int v1 = (i0 + 1 < NB) ? counts[i0 + 1] : 0;
    int v2 = (i0 + 2 < NB) ? counts[i0 + 2] : 0;
    int v3 = (i0 + 3 < NB) ? counts[i0 + 3] : 0;
    int lsum = v0 + v1 + v2 + v3;
    t[tid] = lsum;
    __syncthreads();
#pragma unroll
    for (int off = 1; off < 256; off <<= 1) {
        int x = (tid >= off) ? t[tid - off] : 0;
        __syncthreads();
        t[tid] += x;
        __syncthreads();
    }
    int excl = t[tid] - lsum;
    if (i0 + 0 < NB) { offsets[i0 + 0] = excl;                cursor[i0 + 0] = excl; }
    if (i0 + 1 < NB) { offsets[i0 + 1] = excl + v0;           cursor[i0 + 1] = excl + v0; }
    if (i0 + 2 < NB) { offsets[i0 + 2] = excl + v0 + v1;      cursor[i0 + 2] = excl + v0 + v1; }
    if (i0 + 3 < NB) { offsets[i0 + 3] = excl + v0 + v1 + v2; cursor[i0 + 3] = excl + v0 + v1 + v2; }
    if (tid == 0) offsets[NB] = N_EDGES;
}

// ---------------------------------------------------------------------------
// Block-local counting sort + run-reserved writeout.
// Each block: 4096 edges -> sorted-by-bucket LDS buffer -> streamed out in
// sorted order (consecutive lanes hit consecutive addresses within runs).
// Global atomics: one per (block, nonempty bucket) for run reservation.
// ---------------------------------------------------------------------------
__global__ __launch_bounds__(256) void k_sortscatter(const int* __restrict__ src,
                                                     const int* __restrict__ dst,
                                                     int* __restrict__ cursor,
                                                     unsigned* __restrict__ pairs) {
    __shared__ int hist[NBPAD];        // then reused as placement counters
    __shared__ int lbase[NBPAD];
    __shared__ int gbase[NB];
    __shared__ int tscan[256];
    __shared__ unsigned sorted[SCHUNK];
    __shared__ unsigned short bId[SCHUNK];

    int tid = threadIdx.x;
    int base = blockIdx.x * SCHUNK;
    int nval = N_EDGES - base;
    if (nval > SCHUNK) nval = SCHUNK;

    for (int i = tid; i < NBPAD; i += 256) hist[i] = 0;
    __syncthreads();

    int varr[16];
    int barr[16];
#pragma unroll
    for (int k = 0; k < 16; ++k) {
        int e = base + k * 256 + tid;
        if (e < N_EDGES) {
            int s = src[e];
            int d = dst[e];
            varr[k] = (s << BSHIFT) | (d & (BNODES - 1));
            int b = d >> BSHIFT;
            barr[k] = b;
            atomicAdd(&hist[b], 1);
        } else {
            barr[k] = -1;
        }
    }
    __syncthreads();

    // exclusive scan hist -> lbase (4 elems per thread)
    int i0 = tid * 4;
    int h0 = hist[i0], h1 = hist[i0 + 1], h2 = hist[i0 + 2], h3 = hist[i0 + 3];
    int lsum = h0 + h1 + h2 + h3;
    tscan[tid] = lsum;
    __syncthreads();
#pragma unroll
    for (int off = 1; off < 256; off <<= 1) {
        int x = (tid >= off) ? tscan[tid - off] : 0;
        __syncthreads();
        tscan[tid] += x;
        __syncthreads();
    }
    int excl = tscan[tid] - lsum;
    lbase[i0 + 0] = excl;
    lbase[i0 + 1] = excl + h0;
    lbase[i0 + 2] = excl + h0 + h1;
    lbase[i0 + 3] = excl + h0 + h1 + h2;
    __syncthreads();

    // reserve global run space (<=1 atomic per bucket per block)
    for (int i = tid; i < NB; i += 256) {
        int c = hist[i];
        if (c > 0) gbase[i] = atomicAdd(&cursor[i], c);
    }
    __syncthreads();
    for (int i = tid; i < NBPAD; i += 256) hist[i] = 0;   // -> placement cnt
    __syncthreads();

    // place into sorted LDS order
#pragma unroll
    for (int k = 0; k < 16; ++k) {
        int b = barr[k];
        if (b >= 0) {
            int r = atomicAdd(&hist[b], 1);
            int p = lbase[b] + r;
            sorted[p] = (unsigned)varr[k];
            bId[p] = (unsigned short)b;
        }
    }
    __syncthreads();

    // stream out in sorted order: consecutive i -> consecutive global addrs
    for (int i = tid; i < nval; i += 256) {
        int b = bId[i];
        pairs[gbase[b] + (i - lbase[b])] = sorted[i];
    }
}

// ---------------------------------------------------------------------------
// Y = feat @ W1 -> packed bf16. Thread per node, float4 row loads, W1 in LDS.
// ---------------------------------------------------------------------------
__global__ __launch_bounds__(256) void k_mm1(const float* __restrict__ feat,
                                             const float* __restrict__ W1,
                                             unsigned* __restrict__ Yu) {
    __shared__ float sW[D_IN * D_HID];  // 8 KB
    for (int i = threadIdx.x; i < D_IN * D_HID; i += 256)
        sW[i] = W1[i];
    __syncthreads();

    int n = blockIdx.x * 256 + threadIdx.x;
    if (n >= N_NODES) return;

    const float4* f4 = (const float4*)(feat + (size_t)n * D_IN);
    const float4* sW4 = (const float4*)sW;

    float4 acc[4];
#pragma unroll
    for (int q = 0; q < 4; ++q) acc[q] = make_float4(0.f, 0.f, 0.f, 0.f);

#pragma unroll 8
    for (int kq = 0; kq < 32; ++kq) {
        float4 f = f4[kq];
        int k0 = kq * 4;
#pragma unroll
        for (int jq = 0; jq < 4; ++jq) {
            float4 w0 = sW4[(k0 + 0) * 4 + jq];
            float4 w1 = sW4[(k0 + 1) * 4 + jq];
            float4 w2 = sW4[(k0 + 2) * 4 + jq];
            float4 w3 = sW4[(k0 + 3) * 4 + jq];
            acc[jq].x += f.x * w0.x + f.y * w1.x + f.z * w2.x + f.w * w3.x;
            acc[jq].y += f.x * w0.y + f.y * w1.y + f.z * w2.y + f.w * w3.y;
            acc[jq].z += f.x * w0.z + f.y * w1.z + f.z * w2.z + f.w * w3.z;
            acc[jq].w += f.x * w0.w + f.y * w1.w + f.z * w2.w + f.w * w3.w;
        }
    }
    uint4 o0, o1;
    o0.x = bf_pack(acc[0].x, acc[0].y);
    o0.y = bf_pack(acc[0].z, acc[0].w);
    o0.z = bf_pack(acc[1].x, acc[1].y);
    o0.w = bf_pack(acc[1].z, acc[1].w);
    o1.x = bf_pack(acc[2].x, acc[2].y);
    o1.y = bf_pack(acc[2].z, acc[2].w);
    o1.z = bf_pack(acc[3].x, acc[3].y);
    o1.w = bf_pack(acc[3].z, acc[3].w);
    uint4* y = (uint4*)(Yu + (size_t)n * 8);
    y[0] = o0;
    y[1] = o1;
}

// ---------------------------------------------------------------------------
// Layer-1 aggregation per bucket: 8 lanes/edge, dword gathers, LDS fp32
// atomics; fused bias+ReLU epilogue -> packed bf16 H1.
// ---------------------------------------------------------------------------
__global__ __launch_bounds__(256) void k_agg1(const int* __restrict__ offsets,
                                              const unsigned* __restrict__ pairs,
                                              const unsigned* __restrict__ Yu,
                                              const float* __restrict__ b1,
                                              unsigned* __restrict__ H1u) {
    __shared__ float acc[BNODES * D_HID];  // 8 KB
    __shared__ float sB[D_HID];
    int tid = threadIdx.x;
    for (int i = tid; i < BNODES * D_HID; i += 256) acc[i] = 0.f;
    if (tid < D_HID) sB[tid] = b1[tid];
    __syncthreads();

    int b = blockIdx.x;
    int beg = offsets[b], end = offsets[b + 1];
    int c = tid & 7;
    for (int i = beg + (tid >> 3); i < end; i += 32) {
        unsigned v = pairs[i];
        int s  = v >> BSHIFT;
        int ln = v & (BNODES - 1);
        unsigned dw = Yu[(size_t)s * 8 + c];
        atomicAdd(&acc[ln * D_HID + 2 * c],     bf_lo(dw));
        atomicAdd(&acc[ln * D_HID + 2 * c + 1], bf_hi(dw));
    }
    __syncthreads();

    int nodebase = b * BNODES;
    for (int t = tid; t < BNODES * 8; t += 256) {
        int n = t >> 3, cp = t & 7;
        int node = nodebase + n;
        if (node < N_NODES) {
            float f0 = acc[n * D_HID + 2 * cp]     + sB[2 * cp];
            float f1 = acc[n * D_HID + 2 * cp + 1] + sB[2 * cp + 1];
            f0 = fmaxf(f0, 0.f);
            f1 = fmaxf(f1, 0.f);
            H1u[(size_t)node * 8 + cp] = bf_pack(f0, f1);
        }
    }
}

// ---------------------------------------------------------------------------
// Layer-2 aggregation per bucket + fused mm2 epilogue: out = agg @ W2 + b2.
// ---------------------------------------------------------------------------
__global__ __launch_bounds__(256) void k_agg2(const int* __restrict__ offsets,
                                              const unsigned* __restrict__ pairs,
                                              const unsigned* __restrict__ H1u,
                                              const float* __restrict__ W2,
                                              const float* __restrict__ b2,
                                              float* __restrict__ out) {
    __shared__ float acc[BNODES * D_HID];  // 8 KB
    __shared__ float sW2[D_HID * D_OUT];   // 2 KB
    __shared__ float sb2[D_OUT];
    int tid = threadIdx.x;
    for (int i = tid; i < BNODES * D_HID; i += 256) acc[i] = 0.f;
    for (int i = tid; i < D_HID * D_OUT; i += 256) sW2[i] = W2[i];
    if (tid < D_OUT) sb2[tid] = b2[tid];
    __syncthreads();

    int b = blockIdx.x;
    int beg = offsets[b], end = offsets[b + 1];
    int c = tid & 7;
    for (int i = beg + (tid >> 3); i < end; i += 32) {
        unsigned v = pairs[i];
        int s  = v >> BSHIFT;
        int ln = v & (BNODES - 1);
        unsigned dw = H1u[(size_t)s * 8 + c];
        atomicAdd(&acc[ln * D_HID + 2 * c],     bf_lo(dw));
        atomicAdd(&acc[ln * D_HID + 2 * c + 1], bf_hi(dw));
    }
    __syncthreads();

    int nodebase = b * BNODES;
    for (int t = tid; t < BNODES * D_OUT; t += 256) {
        int n = t >> 5, o = t & 31;
        int node = nodebase + n;
        if (node < N_NODES) {
            float a = sb2[o];
#pragma unroll
            for (int jj = 0; jj < D_HID; ++jj)
                a = fmaf(acc[n * D_HID + jj], sW2[jj * D_OUT + o], a);
            out[(size_t)node * D_OUT + o] = a;
        }
    }
}

// ---------------------------------------------------------------------------
extern "C" void kernel_launch(void* const* d_in, const int* in_sizes, int n_in,
                              void* d_out, int out_size, void* d_ws, size_t ws_size,
                              hipStream_t stream) {
    const float* feat = (const float*)d_in[0];
    const int*   src  = (const int*)d_in[1];
    const int*   dst  = (const int*)d_in[2];
    const float* W1   = (const float*)d_in[3];
    const float* b1   = (const float*)d_in[4];
    const float* W2   = (const float*)d_in[5];
    const float* b2   = (const float*)d_in[6];
    float* out = (float*)d_out;

    // ws layout:
    //   [0      , 6.4M )  pairs   (u32, 1.6M) bucket-grouped packed edges
    //   [6.4M   , 9.6M )  Y       (bf16x16 rows, packed dwords)
    //   [9.6M   , 12.8M)  H1      (bf16x16 rows, packed dwords)
    //   [12.8M  , +4K  )  counts  (NB ints)
    //   [+4K    , +8K  )  offsets (NB+1 ints)
    //   [+8K    , +12K )  cursor  (NB ints)
    char* base = (char*)d_ws;
    unsigned* pairs   = (unsigned*)(base);
    unsigned* Yu      = (unsigned*)(base + 6400000);
    unsigned* H1u     = (unsigned*)(base + 9600000);
    int*      counts  = (int*)(base + 12800000);
    int*      offsets = (int*)(base + 12800000 + 4096);
    int*      cursor  = (int*)(base + 12800000 + 8192);

    hipMemsetAsync(counts, 0, NB * sizeof(int), stream);

    // CSR-by-bucket build
    k_hist       <<<SBLOCKS, 256, 0, stream>>>(dst, counts);
    k_scan       <<<1, 256, 0, stream>>>(counts, offsets, cursor);
    k_sortscatter<<<SBLOCKS, 256, 0, stream>>>(src, dst, cursor, pairs);

    // layer 1: project (cheap order) then bucket-aggregate (fused bias+ReLU)
    k_mm1 <<<(N_NODES + 255) / 256, 256, 0, stream>>>(feat, W1, Yu);
    k_agg1<<<NB, 256, 0, stream>>>(offsets, pairs, Yu, b1, H1u);

    // layer 2: bucket-aggregate with fused mm2 epilogue
    k_agg2<<<NB, 256, 0, stream>>>(offsets, pairs, H1u, W2, b2, out);
}

// Round 5
// 381.816 us; speedup vs baseline: 1.5409x; 1.0881x over previous
//
#include <hip/hip_runtime.h>
#include <hip/hip_bf16.h>

#define N_NODES 100000
#define N_EDGES 1600000
#define D_IN    128
#define D_HID   16
#define D_OUT   32

#define BSHIFT 6
#define BNODES 64                  // nodes per bucket
#define NB 1563                    // ceil(100000/64)
#define NBPAD2 2048                // scan padding (256 threads x 8)
#define ASTRIDE 17                 // padded LDS accumulator row stride
#define SCHUNK 4096                // edges per sort block
#define SBLOCKS 391                // ceil(1600000/4096)

// bf16x2 helpers -------------------------------------------------------------
__device__ inline float bf_lo(unsigned dw) { return __uint_as_float(dw << 16); }
__device__ inline float bf_hi(unsigned dw) { return __uint_as_float(dw & 0xffff0000u); }
__device__ inline unsigned bf_pack(float f0, float f1) {
    union { __hip_bfloat16 h[2]; unsigned u; } pu;
    pu.h[0] = __float2bfloat16(f0);
    pu.h[1] = __float2bfloat16(f1);
    return pu.u;
}

// ---------------------------------------------------------------------------
// Histogram of dst buckets (LDS pre-aggregation, then global atomics).
// ---------------------------------------------------------------------------
__global__ __launch_bounds__(256) void k_hist(const int* __restrict__ dst,
                                              int* __restrict__ counts) {
    __shared__ int h[NB];
    int tid = threadIdx.x;
    for (int i = tid; i < NB; i += 256) h[i] = 0;
    __syncthreads();
    int base = blockIdx.x * SCHUNK;
#pragma unroll
    for (int k = 0; k < 16; ++k) {
        int e = base + k * 256 + tid;
        if (e < N_EDGES) atomicAdd(&h[dst[e] >> BSHIFT], 1);
    }
    __syncthreads();
    for (int i = tid; i < NB; i += 256) {
        int c = h[i];
        if (c) atomicAdd(&counts[i], c);
    }
}

// ---------------------------------------------------------------------------
// Exclusive scan of NB counts -> offsets[NB+1] and mutable cursor copy.
// 256 threads x 8 elems.
// ---------------------------------------------------------------------------
__global__ __launch_bounds__(256) void k_scan(const int* __restrict__ counts,
                                              int* __restrict__ offsets,
                                              int* __restrict__ cursor) {
    __shared__ int t[256];
    int tid = threadIdx.x;
    int i0 = tid * 8;
    int v[8];
    int lsum = 0;
#pragma unroll
    for (int m = 0; m < 8; ++m) {
        int idx = i0 + m;
        v[m] = (idx < NB) ? counts[idx] : 0;
        lsum += v[m];
    }
    t[tid] = lsum;
    __syncthreads();
#pragma unroll
    for (int off = 1; off < 256; off <<= 1) {
        int x = (tid >= off) ? t[tid - off] : 0;
        __syncthreads();
        t[tid] += x;
        __syncthreads();
    }
    int excl = t[tid] - lsum;
#pragma unroll
    for (int m = 0; m < 8; ++m) {
        int idx = i0 + m;
        if (idx < NB) { offsets[idx] = excl; cursor[idx] = excl; }
        excl += v[m];
    }
    if (tid == 0) offsets[NB] = N_EDGES;
}

// ---------------------------------------------------------------------------
// Block-local counting sort + run-reserved writeout (grouped by dst bucket).
// ---------------------------------------------------------------------------
__global__ __launch_bounds__(256) void k_sortscatter(const int* __restrict__ src,
                                                     const int* __restrict__ dst,
                                                     int* __restrict__ cursor,
                                                     unsigned* __restrict__ pairs) {
    __shared__ int hist[NBPAD2];       // then reused as placement counters
    __shared__ int lbase[NBPAD2];
    __shared__ int gbase[NB];
    __shared__ int tscan[256];
    __shared__ unsigned sorted[SCHUNK];
    __shared__ unsigned short bId[SCHUNK];

    int tid = threadIdx.x;
    int base = blockIdx.x * SCHUNK;
    int nval = N_EDGES - base;
    if (nval > SCHUNK) nval = SCHUNK;

    for (int i = tid; i < NBPAD2; i += 256) hist[i] = 0;
    __syncthreads();

    int varr[16];
    int barr[16];
#pragma unroll
    for (int k = 0; k < 16; ++k) {
        int e = base + k * 256 + tid;
        if (e < N_EDGES) {
            int s = src[e];
            int d = dst[e];
            varr[k] = (s << BSHIFT) | (d & (BNODES - 1));
            int b = d >> BSHIFT;
            barr[k] = b;
            atomicAdd(&hist[b], 1);
        } else {
            barr[k] = -1;
        }
    }
    __syncthreads();

    // exclusive scan hist -> lbase (8 elems per thread over NBPAD2)
    int i0 = tid * 8;
    int hv[8];
    int lsum = 0;
#pragma unroll
    for (int m = 0; m < 8; ++m) { hv[m] = hist[i0 + m]; lsum += hv[m]; }
    tscan[tid] = lsum;
    __syncthreads();
#pragma unroll
    for (int off = 1; off < 256; off <<= 1) {
        int x = (tid >= off) ? tscan[tid - off] : 0;
        __syncthreads();
        tscan[tid] += x;
        __syncthreads();
    }
    int excl = tscan[tid] - lsum;
#pragma unroll
    for (int m = 0; m < 8; ++m) { lbase[i0 + m] = excl; excl += hv[m]; }
    __syncthreads();

    // reserve global run space (<=1 atomic per bucket per block)
    for (int i = tid; i < NB; i += 256) {
        int c = hist[i];
        if (c > 0) gbase[i] = atomicAdd(&cursor[i], c);
    }
    __syncthreads();
    for (int i = tid; i < NBPAD2; i += 256) hist[i] = 0;   // -> placement cnt
    __syncthreads();

    // place into sorted LDS order
#pragma unroll
    for (int k = 0; k < 16; ++k) {
        int b = barr[k];
        if (b >= 0) {
            int r = atomicAdd(&hist[b], 1);
            int p = lbase[b] + r;
            sorted[p] = (unsigned)varr[k];
            bId[p] = (unsigned short)b;
        }
    }
    __syncthreads();

    // stream out in sorted order: consecutive i -> consecutive global addrs
    for (int i = tid; i < nval; i += 256) {
        int b = bId[i];
        pairs[gbase[b] + (i - lbase[b])] = sorted[i];
    }
}

// ---------------------------------------------------------------------------
// Y = feat @ W1 -> packed bf16. Thread per node, float4 row loads, W1 in LDS.
// ---------------------------------------------------------------------------
__global__ __launch_bounds__(256) void k_mm1(const float* __restrict__ feat,
                                             const float* __restrict__ W1,
                                             unsigned* __restrict__ Yu) {
    __shared__ float sW[D_IN * D_HID];  // 8 KB
    for (int i = threadIdx.x; i < D_IN * D_HID; i += 256)
        sW[i] = W1[i];
    __syncthreads();

    int n = blockIdx.x * 256 + threadIdx.x;
    if (n >= N_NODES) return;

    const float4* f4 = (const float4*)(feat + (size_t)n * D_IN);
    const float4* sW4 = (const float4*)sW;

    float4 acc[4];
#pragma unroll
    for (int q = 0; q < 4; ++q) acc[q] = make_float4(0.f, 0.f, 0.f, 0.f);

#pragma unroll 8
    for (int kq = 0; kq < 32; ++kq) {
        float4 f = f4[kq];
        int k0 = kq * 4;
#pragma unroll
        for (int jq = 0; jq < 4; ++jq) {
            float4 w0 = sW4[(k0 + 0) * 4 + jq];
            float4 w1 = sW4[(k0 + 1) * 4 + jq];
            float4 w2 = sW4[(k0 + 2) * 4 + jq];
            float4 w3 = sW4[(k0 + 3) * 4 + jq];
            acc[jq].x += f.x * w0.x + f.y * w1.x + f.z * w2.x + f.w * w3.x;
            acc[jq].y += f.x * w0.y + f.y * w1.y + f.z * w2.y + f.w * w3.y;
            acc[jq].z += f.x * w0.z + f.y * w1.z + f.z * w2.z + f.w * w3.z;
            acc[jq].w += f.x * w0.w + f.y * w1.w + f.z * w2.w + f.w * w3.w;
        }
    }
    uint4 o0, o1;
    o0.x = bf_pack(acc[0].x, acc[0].y);
    o0.y = bf_pack(acc[0].z, acc[0].w);
    o0.z = bf_pack(acc[1].x, acc[1].y);
    o0.w = bf_pack(acc[1].z, acc[1].w);
    o1.x = bf_pack(acc[2].x, acc[2].y);
    o1.y = bf_pack(acc[2].z, acc[2].w);
    o1.z = bf_pack(acc[3].x, acc[3].y);
    o1.w = bf_pack(acc[3].z, acc[3].w);
    uint4* y = (uint4*)(Yu + (size_t)n * 8);
    y[0] = o0;
    y[1] = o1;
}

// ---------------------------------------------------------------------------
// Layer-1 aggregation per bucket: 8 lanes/edge, dword gathers, 4x unrolled
// (4 independent gather chains in flight), padded-stride LDS fp32 atomics;
// fused bias+ReLU epilogue -> packed bf16 H1.
// ---------------------------------------------------------------------------
__global__ __launch_bounds__(256) void k_agg1(const int* __restrict__ offsets,
                                              const unsigned* __restrict__ pairs,
                                              const unsigned* __restrict__ Yu,
                                              const float* __restrict__ b1,
                                              unsigned* __restrict__ H1u) {
    __shared__ float acc[BNODES * ASTRIDE];  // 4.25 KB
    __shared__ float sB[D_HID];
    int tid = threadIdx.x;
    for (int i = tid; i < BNODES * ASTRIDE; i += 256) acc[i] = 0.f;
    if (tid < D_HID) sB[tid] = b1[tid];
    __syncthreads();

    int b = blockIdx.x;
    int beg = offsets[b], end = offsets[b + 1];
    int c = tid & 7;
    int i = beg + (tid >> 3);

    for (; i + 96 < end; i += 128) {
        unsigned p0 = pairs[i];
        unsigned p1 = pairs[i + 32];
        unsigned p2 = pairs[i + 64];
        unsigned p3 = pairs[i + 96];
        unsigned d0 = Yu[(size_t)(p0 >> BSHIFT) * 8 + c];
        unsigned d1 = Yu[(size_t)(p1 >> BSHIFT) * 8 + c];
        unsigned d2 = Yu[(size_t)(p2 >> BSHIFT) * 8 + c];
        unsigned d3 = Yu[(size_t)(p3 >> BSHIFT) * 8 + c];
        atomicAdd(&acc[(p0 & (BNODES - 1)) * ASTRIDE + 2 * c],     bf_lo(d0));
        atomicAdd(&acc[(p0 & (BNODES - 1)) * ASTRIDE + 2 * c + 1], bf_hi(d0));
        atomicAdd(&acc[(p1 & (BNODES - 1)) * ASTRIDE + 2 * c],     bf_lo(d1));
        atomicAdd(&acc[(p1 & (BNODES - 1)) * ASTRIDE + 2 * c + 1], bf_hi(d1));
        atomicAdd(&acc[(p2 & (BNODES - 1)) * ASTRIDE + 2 * c],     bf_lo(d2));
        atomicAdd(&acc[(p2 & (BNODES - 1)) * ASTRIDE + 2 * c + 1], bf_hi(d2));
        atomicAdd(&acc[(p3 & (BNODES - 1)) * ASTRIDE + 2 * c],     bf_lo(d3));
        atomicAdd(&acc[(p3 & (BNODES - 1)) * ASTRIDE + 2 * c + 1], bf_hi(d3));
    }
    for (; i < end; i += 32) {
        unsigned p = pairs[i];
        unsigned dw = Yu[(size_t)(p >> BSHIFT) * 8 + c];
        atomicAdd(&acc[(p & (BNODES - 1)) * ASTRIDE + 2 * c],     bf_lo(dw));
        atomicAdd(&acc[(p & (BNODES - 1)) * ASTRIDE + 2 * c + 1], bf_hi(dw));
    }
    __syncthreads();

    int nodebase = b * BNODES;
    for (int t = tid; t < BNODES * 8; t += 256) {
        int n = t >> 3, cp = t & 7;
        int node = nodebase + n;
        if (node < N_NODES) {
            float f0 = acc[n * ASTRIDE + 2 * cp]     + sB[2 * cp];
            float f1 = acc[n * ASTRIDE + 2 * cp + 1] + sB[2 * cp + 1];
            f0 = fmaxf(f0, 0.f);
            f1 = fmaxf(f1, 0.f);
            H1u[(size_t)node * 8 + cp] = bf_pack(f0, f1);
        }
    }
}

// ---------------------------------------------------------------------------
// Layer-2 aggregation per bucket + fused mm2 epilogue: out = agg @ W2 + b2.
// ---------------------------------------------------------------------------
__global__ __launch_bounds__(256) void k_agg2(const int* __restrict__ offsets,
                                              const unsigned* __restrict__ pairs,
                                              const unsigned* __restrict__ H1u,
                                              const float* __restrict__ W2,
                                              const float* __restrict__ b2,
                                              float* __restrict__ out) {
    __shared__ float acc[BNODES * ASTRIDE];  // 4.25 KB
    __shared__ float sW2[D_HID * D_OUT];     // 2 KB
    __shared__ float sb2[D_OUT];
    int tid = threadIdx.x;
    for (int i = tid; i < BNODES * ASTRIDE; i += 256) acc[i] = 0.f;
    for (int i = tid; i < D_HID * D_OUT; i += 256) sW2[i] = W2[i];
    if (tid < D_OUT) sb2[tid] = b2[tid];
    __syncthreads();

    int b = blockIdx.x;
    int beg = offsets[b], end = offsets[b + 1];
    int c = tid & 7;
    int i = beg + (tid >> 3);

    for (; i + 96 < end; i += 128) {
        unsigned p0 = pairs[i];
        unsigned p1 = pairs[i + 32];
        unsigned p2 = pairs[i + 64];
        unsigned p3 = pairs[i + 96];
        unsigned d0 = H1u[(size_t)(p0 >> BSHIFT) * 8 + c];
        unsigned d1 = H1u[(size_t)(p1 >> BSHIFT) * 8 + c];
        unsigned d2 = H1u[(size_t)(p2 >> BSHIFT) * 8 + c];
        unsigned d3 = H1u[(size_t)(p3 >> BSHIFT) * 8 + c];
        atomicAdd(&acc[(p0 & (BNODES - 1)) * ASTRIDE + 2 * c],     bf_lo(d0));
        atomicAdd(&acc[(p0 & (BNODES - 1)) * ASTRIDE + 2 * c + 1], bf_hi(d0));
        atomicAdd(&acc[(p1 & (BNODES - 1)) * ASTRIDE + 2 * c],     bf_lo(d1));
        atomicAdd(&acc[(p1 & (BNODES - 1)) * ASTRIDE + 2 * c + 1], bf_hi(d1));
        atomicAdd(&acc[(p2 & (BNODES - 1)) * ASTRIDE + 2 * c],     bf_lo(d2));
        atomicAdd(&acc[(p2 & (BNODES - 1)) * ASTRIDE + 2 * c + 1], bf_hi(d2));
        atomicAdd(&acc[(p3 & (BNODES - 1)) * ASTRIDE + 2 * c],     bf_lo(d3));
        atomicAdd(&acc[(p3 & (BNODES - 1)) * ASTRIDE + 2 * c + 1], bf_hi(d3));
    }
    for (; i < end; i += 32) {
        unsigned p = pairs[i];
        unsigned dw = H1u[(size_t)(p >> BSHIFT) * 8 + c];
        atomicAdd(&acc[(p & (BNODES - 1)) * ASTRIDE + 2 * c],     bf_lo(dw));
        atomicAdd(&acc[(p & (BNODES - 1)) * ASTRIDE + 2 * c + 1], bf_hi(dw));
    }
    __syncthreads();

    int nodebase = b * BNODES;
    for (int t = tid; t < BNODES * D_OUT; t += 256) {
        int n = t >> 5, o = t & 31;
        int node = nodebase + n;
        if (node < N_NODES) {
            float a = sb2[o];
#pragma unroll
            for (int jj = 0; jj < D_HID; ++jj)
                a = fmaf(acc[n * ASTRIDE + jj], sW2[jj * D_OUT + o], a);
            out[(size_t)node * D_OUT + o] = a;
        }
    }
}

// ---------------------------------------------------------------------------
extern "C" void kernel_launch(void* const* d_in, const int* in_sizes, int n_in,
                              void* d_out, int out_size, void* d_ws, size_t ws_size,
                              hipStream_t stream) {
    const float* feat = (const float*)d_in[0];
    const int*   src  = (const int*)d_in[1];
    const int*   dst  = (const int*)d_in[2];
    const float* W1   = (const float*)d_in[3];
    const float* b1   = (const float*)d_in[4];
    const float* W2   = (const float*)d_in[5];
    const float* b2   = (const float*)d_in[6];
    float* out = (float*)d_out;

    // ws layout:
    //   [0      , 6.4M )  pairs   (u32, 1.6M) bucket-grouped packed edges
    //   [6.4M   , 9.6M )  Y       (bf16x16 rows, packed dwords)
    //   [9.6M   , 12.8M)  H1      (bf16x16 rows, packed dwords)
    //   [12.8M  , +8K  )  counts  (NB ints)
    //   [+8K    , +16K )  offsets (NB+1 ints)
    //   [+16K   , +24K )  cursor  (NB ints)
    char* base = (char*)d_ws;
    unsigned* pairs   = (unsigned*)(base);
    unsigned* Yu      = (unsigned*)(base + 6400000);
    unsigned* H1u     = (unsigned*)(base + 9600000);
    int*      counts  = (int*)(base + 12800000);
    int*      offsets = (int*)(base + 12800000 + 8192);
    int*      cursor  = (int*)(base + 12800000 + 16384);

    hipMemsetAsync(counts, 0, NB * sizeof(int), stream);

    // CSR-by-bucket build
    k_hist       <<<SBLOCKS, 256, 0, stream>>>(dst, counts);
    k_scan       <<<1, 256, 0, stream>>>(counts, offsets, cursor);
    k_sortscatter<<<SBLOCKS, 256, 0, stream>>>(src, dst, cursor, pairs);

    // layer 1: project (cheap order) then bucket-aggregate (fused bias+ReLU)
    k_mm1 <<<(N_NODES + 255) / 256, 256, 0, stream>>>(feat, W1, Yu);
    k_agg1<<<NB, 256, 0, stream>>>(offsets, pairs, Yu, b1, H1u);

    // layer 2: bucket-aggregate with fused mm2 epilogue
    k_agg2<<<NB, 256, 0, stream>>>(offsets, pairs, H1u, W2, b2, out);
}

// Round 6
// 122.919 us; speedup vs baseline: 4.7865x; 3.1062x over previous
//
#include <hip/hip_runtime.h>
#include <hip/hip_bf16.h>

#define N_NODES 100000
#define N_EDGES 1600000
#define D_IN    128
#define D_HID   16
#define D_OUT   32

#define BSHIFT 6
#define BNODES 64                  // nodes per bucket
#define NB 1563                    // ceil(100000/64)
#define NBPAD2 2048                // scan padding (256 threads x 8)
#define SCHUNK 4096                // edges per sort block
#define SBLOCKS 391                // ceil(1600000/4096)
#define SORTCAP 2048               // per-bucket edge cap (mean 1024, sd 32 -> safe)

// bf16x2 helpers -------------------------------------------------------------
__device__ inline float bf_lo(unsigned dw) { return __uint_as_float(dw << 16); }
__device__ inline float bf_hi(unsigned dw) { return __uint_as_float(dw & 0xffff0000u); }
__device__ inline unsigned bf_pack(float f0, float f1) {
    union { __hip_bfloat16 h[2]; unsigned u; } pu;
    pu.h[0] = __float2bfloat16(f0);
    pu.h[1] = __float2bfloat16(f1);
    return pu.u;
}

// ---------------------------------------------------------------------------
// Histogram of dst buckets (LDS pre-aggregation, then global atomics).
// ---------------------------------------------------------------------------
__global__ __launch_bounds__(256) void k_hist(const int* __restrict__ dst,
                                              int* __restrict__ counts) {
    __shared__ int h[NB];
    int tid = threadIdx.x;
    for (int i = tid; i < NB; i += 256) h[i] = 0;
    __syncthreads();
    int base = blockIdx.x * SCHUNK;
#pragma unroll
    for (int k = 0; k < 16; ++k) {
        int e = base + k * 256 + tid;
        if (e < N_EDGES) atomicAdd(&h[dst[e] >> BSHIFT], 1);
    }
    __syncthreads();
    for (int i = tid; i < NB; i += 256) {
        int c = h[i];
        if (c) atomicAdd(&counts[i], c);
    }
}

// ---------------------------------------------------------------------------
// Exclusive scan of NB counts -> offsets[NB+1] and mutable cursor copy.
// ---------------------------------------------------------------------------
__global__ __launch_bounds__(256) void k_scan(const int* __restrict__ counts,
                                              int* __restrict__ offsets,
                                              int* __restrict__ cursor) {
    __shared__ int t[256];
    int tid = threadIdx.x;
    int i0 = tid * 8;
    int v[8];
    int lsum = 0;
#pragma unroll
    for (int m = 0; m < 8; ++m) {
        int idx = i0 + m;
        v[m] = (idx < NB) ? counts[idx] : 0;
        lsum += v[m];
    }
    t[tid] = lsum;
    __syncthreads();
#pragma unroll
    for (int off = 1; off < 256; off <<= 1) {
        int x = (tid >= off) ? t[tid - off] : 0;
        __syncthreads();
        t[tid] += x;
        __syncthreads();
    }
    int excl = t[tid] - lsum;
#pragma unroll
    for (int m = 0; m < 8; ++m) {
        int idx = i0 + m;
        if (idx < NB) { offsets[idx] = excl; cursor[idx] = excl; }
        excl += v[m];
    }
    if (tid == 0) offsets[NB] = N_EDGES;
}

// ---------------------------------------------------------------------------
// Block-local counting sort + run-reserved writeout (grouped by dst bucket).
// pairs[slot] = (src << 6) | (dst & 63), grouped by bucket.
// ---------------------------------------------------------------------------
__global__ __launch_bounds__(256) void k_sortscatter(const int* __restrict__ src,
                                                     const int* __restrict__ dst,
                                                     int* __restrict__ cursor,
                                                     unsigned* __restrict__ pairs) {
    __shared__ int hist[NBPAD2];       // then reused as placement counters
    __shared__ int lbase[NBPAD2];
    __shared__ int gbase[NB];
    __shared__ int tscan[256];
    __shared__ unsigned sorted[SCHUNK];
    __shared__ unsigned short bId[SCHUNK];

    int tid = threadIdx.x;
    int base = blockIdx.x * SCHUNK;
    int nval = N_EDGES - base;
    if (nval > SCHUNK) nval = SCHUNK;

    for (int i = tid; i < NBPAD2; i += 256) hist[i] = 0;
    __syncthreads();

    int varr[16];
    int barr[16];
#pragma unroll
    for (int k = 0; k < 16; ++k) {
        int e = base + k * 256 + tid;
        if (e < N_EDGES) {
            int s = src[e];
            int d = dst[e];
            varr[k] = (s << BSHIFT) | (d & (BNODES - 1));
            int b = d >> BSHIFT;
            barr[k] = b;
            atomicAdd(&hist[b], 1);
        } else {
            barr[k] = -1;
        }
    }
    __syncthreads();

    int i0 = tid * 8;
    int hv[8];
    int lsum = 0;
#pragma unroll
    for (int m = 0; m < 8; ++m) { hv[m] = hist[i0 + m]; lsum += hv[m]; }
    tscan[tid] = lsum;
    __syncthreads();
#pragma unroll
    for (int off = 1; off < 256; off <<= 1) {
        int x = (tid >= off) ? tscan[tid - off] : 0;
        __syncthreads();
        tscan[tid] += x;
        __syncthreads();
    }
    int excl = tscan[tid] - lsum;
#pragma unroll
    for (int m = 0; m < 8; ++m) { lbase[i0 + m] = excl; excl += hv[m]; }
    __syncthreads();

    for (int i = tid; i < NB; i += 256) {
        int c = hist[i];
        if (c > 0) gbase[i] = atomicAdd(&cursor[i], c);
    }
    __syncthreads();
    for (int i = tid; i < NBPAD2; i += 256) hist[i] = 0;   // -> placement cnt
    __syncthreads();

#pragma unroll
    for (int k = 0; k < 16; ++k) {
        int b = barr[k];
        if (b >= 0) {
            int r = atomicAdd(&hist[b], 1);
            int p = lbase[b] + r;
            sorted[p] = (unsigned)varr[k];
            bId[p] = (unsigned short)b;
        }
    }
    __syncthreads();

    for (int i = tid; i < nval; i += 256) {
        int b = bId[i];
        pairs[gbase[b] + (i - lbase[b])] = sorted[i];
    }
}

// ---------------------------------------------------------------------------
// Per-bucket node sort: one block per bucket. Counting sort by ln (64 keys,
// int LDS atomics only). Rewrites pairs[beg..end) in-place as plain src ids
// sorted by dst node, and emits node_off (per-node CSR offsets).
// ---------------------------------------------------------------------------
__global__ __launch_bounds__(256) void k_nodesort(const int* __restrict__ offsets,
                                                  unsigned* __restrict__ pairs,
                                                  int* __restrict__ node_off) {
    __shared__ unsigned buf[SORTCAP];
    __shared__ int hist[BNODES];
    __shared__ int lbase[BNODES];
    __shared__ int cur[BNODES];

    int tid = threadIdx.x;
    int b = blockIdx.x;
    int beg = offsets[b], end = offsets[b + 1];
    int cnt = end - beg;
    if (cnt > SORTCAP) cnt = SORTCAP;   // statistically impossible (mean 1024, sd 32)

    if (tid < BNODES) hist[tid] = 0;
    __syncthreads();

    for (int i = tid; i < cnt; i += 256) {
        unsigned p = pairs[beg + i];
        buf[i] = p;
        atomicAdd(&hist[p & (BNODES - 1)], 1);
    }
    __syncthreads();

    if (tid == 0) {
        int run = 0;
#pragma unroll
        for (int l = 0; l < BNODES; ++l) {
            lbase[l] = run;
            cur[l] = run;
            run += hist[l];
        }
    }
    __syncthreads();

    if (tid < BNODES) node_off[b * BNODES + tid] = beg + lbase[tid];
    if (b == 0 && tid == 0) node_off[NB * BNODES] = N_EDGES;

    for (int i = tid; i < cnt; i += 256) {
        unsigned p = buf[i];
        int pos = atomicAdd(&cur[p & (BNODES - 1)], 1);
        pairs[beg + pos] = p >> BSHIFT;     // store plain src id, node-sorted
    }
}

// ---------------------------------------------------------------------------
// Y = feat @ W1 -> packed bf16. Thread per node, float4 row loads, W1 in LDS.
// ---------------------------------------------------------------------------
__global__ __launch_bounds__(256) void k_mm1(const float* __restrict__ feat,
                                             const float* __restrict__ W1,
                                             unsigned* __restrict__ Yu) {
    __shared__ float sW[D_IN * D_HID];  // 8 KB
    for (int i = threadIdx.x; i < D_IN * D_HID; i += 256)
        sW[i] = W1[i];
    __syncthreads();

    int n = blockIdx.x * 256 + threadIdx.x;
    if (n >= N_NODES) return;

    const float4* f4 = (const float4*)(feat + (size_t)n * D_IN);
    const float4* sW4 = (const float4*)sW;

    float4 acc[4];
#pragma unroll
    for (int q = 0; q < 4; ++q) acc[q] = make_float4(0.f, 0.f, 0.f, 0.f);

#pragma unroll 8
    for (int kq = 0; kq < 32; ++kq) {
        float4 f = f4[kq];
        int k0 = kq * 4;
#pragma unroll
        for (int jq = 0; jq < 4; ++jq) {
            float4 w0 = sW4[(k0 + 0) * 4 + jq];
            float4 w1 = sW4[(k0 + 1) * 4 + jq];
            float4 w2 = sW4[(k0 + 2) * 4 + jq];
            float4 w3 = sW4[(k0 + 3) * 4 + jq];
            acc[jq].x += f.x * w0.x + f.y * w1.x + f.z * w2.x + f.w * w3.x;
            acc[jq].y += f.x * w0.y + f.y * w1.y + f.z * w2.y + f.w * w3.y;
            acc[jq].z += f.x * w0.z + f.y * w1.z + f.z * w2.z + f.w * w3.z;
            acc[jq].w += f.x * w0.w + f.y * w1.w + f.z * w2.w + f.w * w3.w;
        }
    }
    uint4 o0, o1;
    o0.x = bf_pack(acc[0].x, acc[0].y);
    o0.y = bf_pack(acc[0].z, acc[0].w);
    o0.z = bf_pack(acc[1].x, acc[1].y);
    o0.w = bf_pack(acc[1].z, acc[1].w);
    o1.x = bf_pack(acc[2].x, acc[2].y);
    o1.y = bf_pack(acc[2].z, acc[2].w);
    o1.z = bf_pack(acc[3].x, acc[3].y);
    o1.w = bf_pack(acc[3].z, acc[3].w);
    uint4* y = (uint4*)(Yu + (size_t)n * 8);
    y[0] = o0;
    y[1] = o1;
}

// ---------------------------------------------------------------------------
// Layer-1 aggregation: 8 lanes per node, pure register accumulation over the
// node's sorted edge run (no atomics). 4 independent partial sums for MLP.
// Fused bias+ReLU -> packed bf16 H1.
// ---------------------------------------------------------------------------
__global__ __launch_bounds__(256) void k_agg1(const int* __restrict__ node_off,
                                              const unsigned* __restrict__ csr,
                                              const unsigned* __restrict__ Yu,
                                              const float* __restrict__ bias1,
                                              unsigned* __restrict__ H1u) {
    int tid = threadIdx.x;
    int g = tid >> 3;          // node slot 0..31
    int c = tid & 7;           // channel pair
    int n = blockIdx.x * 32 + g;
    if (n >= N_NODES) return;

    int beg = node_off[n], end = node_off[n + 1];
    float a0 = 0.f, a1 = 0.f, b0 = 0.f, b1v = 0.f;
    float c0 = 0.f, c1 = 0.f, d0f = 0.f, d1f = 0.f;
    int i = beg;
    for (; i + 3 < end; i += 4) {
        unsigned s0 = csr[i],     s1 = csr[i + 1];
        unsigned s2 = csr[i + 2], s3 = csr[i + 3];
        unsigned w0 = Yu[(size_t)s0 * 8 + c];
        unsigned w1 = Yu[(size_t)s1 * 8 + c];
        unsigned w2 = Yu[(size_t)s2 * 8 + c];
        unsigned w3 = Yu[(size_t)s3 * 8 + c];
        a0 += bf_lo(w0); a1 += bf_hi(w0);
        b0 += bf_lo(w1); b1v += bf_hi(w1);
        c0 += bf_lo(w2); c1 += bf_hi(w2);
        d0f += bf_lo(w3); d1f += bf_hi(w3);
    }
    for (; i < end; ++i) {
        unsigned s = csr[i];
        unsigned w = Yu[(size_t)s * 8 + c];
        a0 += bf_lo(w); a1 += bf_hi(w);
    }
    float f0 = (a0 + b0) + (c0 + d0f) + bias1[2 * c];
    float f1 = (a1 + b1v) + (c1 + d1f) + bias1[2 * c + 1];
    f0 = fmaxf(f0, 0.f);
    f1 = fmaxf(f1, 0.f);
    H1u[(size_t)n * 8 + c] = bf_pack(f0, f1);
}

// ---------------------------------------------------------------------------
// Layer-2 aggregation (register accumulation) + fused mm2 epilogue via LDS.
// ---------------------------------------------------------------------------
__global__ __launch_bounds__(256) void k_agg2(const int* __restrict__ node_off,
                                              const unsigned* __restrict__ csr,
                                              const unsigned* __restrict__ H1u,
                                              const float* __restrict__ W2,
                                              const float* __restrict__ b2,
                                              float* __restrict__ out) {
    __shared__ float sacc[32][D_HID + 1];  // 32 nodes x 16 ch, padded
    __shared__ float sW2[D_HID * D_OUT];   // 2 KB
    __shared__ float sb2[D_OUT];
    int tid = threadIdx.x;
    for (int i = tid; i < D_HID * D_OUT; i += 256) sW2[i] = W2[i];
    if (tid < D_OUT) sb2[tid] = b2[tid];

    int g = tid >> 3;
    int c = tid & 7;
    int n = blockIdx.x * 32 + g;

    float a0 = 0.f, a1 = 0.f, b0 = 0.f, b1v = 0.f;
    float c0 = 0.f, c1 = 0.f, d0f = 0.f, d1f = 0.f;
    if (n < N_NODES) {
        int beg = node_off[n], end = node_off[n + 1];
        int i = beg;
        for (; i + 3 < end; i += 4) {
            unsigned s0 = csr[i],     s1 = csr[i + 1];
            unsigned s2 = csr[i + 2], s3 = csr[i + 3];
            unsigned w0 = H1u[(size_t)s0 * 8 + c];
            unsigned w1 = H1u[(size_t)s1 * 8 + c];
            unsigned w2 = H1u[(size_t)s2 * 8 + c];
            unsigned w3 = H1u[(size_t)s3 * 8 + c];
            a0 += bf_lo(w0); a1 += bf_hi(w0);
            b0 += bf_lo(w1); b1v += bf_hi(w1);
            c0 += bf_lo(w2); c1 += bf_hi(w2);
            d0f += bf_lo(w3); d1f += bf_hi(w3);
        }
        for (; i < end; ++i) {
            unsigned s = csr[i];
            unsigned w = H1u[(size_t)s * 8 + c];
            a0 += bf_lo(w); a1 += bf_hi(w);
        }
    }
    sacc[g][2 * c]     = (a0 + b0) + (c0 + d0f);
    sacc[g][2 * c + 1] = (a1 + b1v) + (c1 + d1f);
    __syncthreads();

    // mm2: 32 nodes x 32 outputs = 1024 -> 4 per thread
    for (int t = tid; t < 32 * D_OUT; t += 256) {
        int gg = t >> 5, o = t & 31;
        int node = blockIdx.x * 32 + gg;
        if (node < N_NODES) {
            float a = sb2[o];
#pragma unroll
            for (int j = 0; j < D_HID; ++j)
                a = fmaf(sacc[gg][j], sW2[j * D_OUT + o], a);
            out[(size_t)node * D_OUT + o] = a;
        }
    }
}

// ---------------------------------------------------------------------------
extern "C" void kernel_launch(void* const* d_in, const int* in_sizes, int n_in,
                              void* d_out, int out_size, void* d_ws, size_t ws_size,
                              hipStream_t stream) {
    const float* feat = (const float*)d_in[0];
    const int*   src  = (const int*)d_in[1];
    const int*   dst  = (const int*)d_in[2];
    const float* W1   = (const float*)d_in[3];
    const float* b1   = (const float*)d_in[4];
    const float* W2   = (const float*)d_in[5];
    const float* b2   = (const float*)d_in[6];
    float* out = (float*)d_out;

    // ws layout:
    //   [0      , 6.4M )  pairs/csr (u32, 1.6M)
    //   [6.4M   , 9.6M )  Y   (bf16x16 rows, packed dwords)
    //   [9.6M   , 12.8M)  H1  (bf16x16 rows, packed dwords)
    //   [12.8M  , +8K  )  counts  (NB ints)
    //   [+8K    , +16K )  offsets (NB+1 ints)
    //   [+16K   , +24K )  cursor  (NB ints)
    //   [+24K   , +424K)  node_off (NB*64+1 ints = 100033)
    char* base = (char*)d_ws;
    unsigned* pairs    = (unsigned*)(base);
    unsigned* Yu       = (unsigned*)(base + 6400000);
    unsigned* H1u      = (unsigned*)(base + 9600000);
    int*      counts   = (int*)(base + 12800000);
    int*      offsets  = (int*)(base + 12800000 + 8192);
    int*      cursor   = (int*)(base + 12800000 + 16384);
    int*      node_off = (int*)(base + 12800000 + 24576);

    hipMemsetAsync(counts, 0, NB * sizeof(int), stream);

    // CSR build: bucket-group then per-bucket node sort
    k_hist       <<<SBLOCKS, 256, 0, stream>>>(dst, counts);
    k_scan       <<<1, 256, 0, stream>>>(counts, offsets, cursor);
    k_sortscatter<<<SBLOCKS, 256, 0, stream>>>(src, dst, cursor, pairs);
    k_nodesort   <<<NB, 256, 0, stream>>>(offsets, pairs, node_off);

    // layer 1: project (cheap order) then gather-aggregate (fused bias+ReLU)
    k_mm1 <<<(N_NODES + 255) / 256, 256, 0, stream>>>(feat, W1, Yu);
    k_agg1<<<(N_NODES + 31) / 32, 256, 0, stream>>>(node_off, pairs, Yu, b1, H1u);

    // layer 2: gather-aggregate with fused mm2 epilogue
    k_agg2<<<(N_NODES + 31) / 32, 256, 0, stream>>>(node_off, pairs, H1u, W2, b2, out);
}

// Round 7
// 121.085 us; speedup vs baseline: 4.8590x; 1.0151x over previous
//
#include <hip/hip_runtime.h>
#include <hip/hip_bf16.h>

#define N_NODES 100000
#define N_EDGES 1600000
#define D_IN    128
#define D_HID   16
#define D_OUT   32

#define BSHIFT 6
#define BNODES 64                  // nodes per bucket
#define NB 1563                    // ceil(100000/64)
#define NBPAD2 2048                // scan padding (256 threads x 8)
#define SCHUNK 4096                // edges per sort block
#define SBLOCKS 391                // ceil(1600000/4096)
#define SORTCAP 2048               // per-bucket edge cap (mean 1024, sd 32 -> safe)

// bf16x2 helpers -------------------------------------------------------------
__device__ inline float bf_lo(unsigned dw) { return __uint_as_float(dw << 16); }
__device__ inline float bf_hi(unsigned dw) { return __uint_as_float(dw & 0xffff0000u); }
__device__ inline unsigned bf_pack(float f0, float f1) {
    union { __hip_bfloat16 h[2]; unsigned u; } pu;
    pu.h[0] = __float2bfloat16(f0);
    pu.h[1] = __float2bfloat16(f1);
    return pu.u;
}

// ---------------------------------------------------------------------------
// Zero the counts array (replaces a 40us hipMemsetAsync fill dispatch).
// ---------------------------------------------------------------------------
__global__ __launch_bounds__(256) void k_zero(int* __restrict__ counts) {
    int i = blockIdx.x * 256 + threadIdx.x;
    if (i < NB) counts[i] = 0;
}

// ---------------------------------------------------------------------------
// Histogram of dst buckets (LDS pre-aggregation, then global atomics).
// ---------------------------------------------------------------------------
__global__ __launch_bounds__(256) void k_hist(const int* __restrict__ dst,
                                              int* __restrict__ counts) {
    __shared__ int h[NB];
    int tid = threadIdx.x;
    for (int i = tid; i < NB; i += 256) h[i] = 0;
    __syncthreads();
    int base = blockIdx.x * SCHUNK;
#pragma unroll
    for (int k = 0; k < 16; ++k) {
        int e = base + k * 256 + tid;
        if (e < N_EDGES) atomicAdd(&h[dst[e] >> BSHIFT], 1);
    }
    __syncthreads();
    for (int i = tid; i < NB; i += 256) {
        int c = h[i];
        if (c) atomicAdd(&counts[i], c);
    }
}

// ---------------------------------------------------------------------------
// Exclusive scan of NB counts -> offsets[NB+1] and mutable cursor copy.
// ---------------------------------------------------------------------------
__global__ __launch_bounds__(256) void k_scan(const int* __restrict__ counts,
                                              int* __restrict__ offsets,
                                              int* __restrict__ cursor) {
    __shared__ int t[256];
    int tid = threadIdx.x;
    int i0 = tid * 8;
    int v[8];
    int lsum = 0;
#pragma unroll
    for (int m = 0; m < 8; ++m) {
        int idx = i0 + m;
        v[m] = (idx < NB) ? counts[idx] : 0;
        lsum += v[m];
    }
    t[tid] = lsum;
    __syncthreads();
#pragma unroll
    for (int off = 1; off < 256; off <<= 1) {
        int x = (tid >= off) ? t[tid - off] : 0;
        __syncthreads();
        t[tid] += x;
        __syncthreads();
    }
    int excl = t[tid] - lsum;
#pragma unroll
    for (int m = 0; m < 8; ++m) {
        int idx = i0 + m;
        if (idx < NB) { offsets[idx] = excl; cursor[idx] = excl; }
        excl += v[m];
    }
    if (tid == 0) offsets[NB] = N_EDGES;
}

// ---------------------------------------------------------------------------
// Block-local counting sort + run-reserved writeout (grouped by dst bucket).
// pairs[slot] = (src << 6) | (dst & 63), grouped by bucket.
// ---------------------------------------------------------------------------
__global__ __launch_bounds__(256) void k_sortscatter(const int* __restrict__ src,
                                                     const int* __restrict__ dst,
                                                     int* __restrict__ cursor,
                                                     unsigned* __restrict__ pairs) {
    __shared__ int hist[NBPAD2];       // then reused as placement counters
    __shared__ int lbase[NBPAD2];
    __shared__ int gbase[NB];
    __shared__ int tscan[256];
    __shared__ unsigned sorted[SCHUNK];
    __shared__ unsigned short bId[SCHUNK];

    int tid = threadIdx.x;
    int base = blockIdx.x * SCHUNK;
    int nval = N_EDGES - base;
    if (nval > SCHUNK) nval = SCHUNK;

    for (int i = tid; i < NBPAD2; i += 256) hist[i] = 0;
    __syncthreads();

    int varr[16];
    int barr[16];
#pragma unroll
    for (int k = 0; k < 16; ++k) {
        int e = base + k * 256 + tid;
        if (e < N_EDGES) {
            int s = src[e];
            int d = dst[e];
            varr[k] = (s << BSHIFT) | (d & (BNODES - 1));
            int b = d >> BSHIFT;
            barr[k] = b;
            atomicAdd(&hist[b], 1);
        } else {
            barr[k] = -1;
        }
    }
    __syncthreads();

    int i0 = tid * 8;
    int hv[8];
    int lsum = 0;
#pragma unroll
    for (int m = 0; m < 8; ++m) { hv[m] = hist[i0 + m]; lsum += hv[m]; }
    tscan[tid] = lsum;
    __syncthreads();
#pragma unroll
    for (int off = 1; off < 256; off <<= 1) {
        int x = (tid >= off) ? tscan[tid - off] : 0;
        __syncthreads();
        tscan[tid] += x;
        __syncthreads();
    }
    int excl = tscan[tid] - lsum;
#pragma unroll
    for (int m = 0; m < 8; ++m) { lbase[i0 + m] = excl; excl += hv[m]; }
    __syncthreads();

    for (int i = tid; i < NB; i += 256) {
        int c = hist[i];
        if (c > 0) gbase[i] = atomicAdd(&cursor[i], c);
    }
    __syncthreads();
    for (int i = tid; i < NBPAD2; i += 256) hist[i] = 0;   // -> placement cnt
    __syncthreads();

#pragma unroll
    for (int k = 0; k < 16; ++k) {
        int b = barr[k];
        if (b >= 0) {
            int r = atomicAdd(&hist[b], 1);
            int p = lbase[b] + r;
            sorted[p] = (unsigned)varr[k];
            bId[p] = (unsigned short)b;
        }
    }
    __syncthreads();

    for (int i = tid; i < nval; i += 256) {
        int b = bId[i];
        pairs[gbase[b] + (i - lbase[b])] = sorted[i];
    }
}

// ---------------------------------------------------------------------------
// Per-bucket node sort: one block per bucket. Counting sort by ln (64 keys,
// int LDS atomics only). Rewrites pairs[beg..end) in-place as plain src ids
// sorted by dst node, and emits node_off (per-node CSR offsets).
// ---------------------------------------------------------------------------
__global__ __launch_bounds__(256) void k_nodesort(const int* __restrict__ offsets,
                                                  unsigned* __restrict__ pairs,
                                                  int* __restrict__ node_off) {
    __shared__ unsigned buf[SORTCAP];
    __shared__ int hist[BNODES];
    __shared__ int lbase[BNODES];
    __shared__ int cur[BNODES];

    int tid = threadIdx.x;
    int b = blockIdx.x;
    int beg = offsets[b], end = offsets[b + 1];
    int cnt = end - beg;
    if (cnt > SORTCAP) cnt = SORTCAP;   // statistically impossible (mean 1024, sd 32)

    if (tid < BNODES) hist[tid] = 0;
    __syncthreads();

    for (int i = tid; i < cnt; i += 256) {
        unsigned p = pairs[beg + i];
        buf[i] = p;
        atomicAdd(&hist[p & (BNODES - 1)], 1);
    }
    __syncthreads();

    if (tid == 0) {
        int run = 0;
#pragma unroll
        for (int l = 0; l < BNODES; ++l) {
            lbase[l] = run;
            cur[l] = run;
            run += hist[l];
        }
    }
    __syncthreads();

    if (tid < BNODES) node_off[b * BNODES + tid] = beg + lbase[tid];
    if (b == 0 && tid == 0) node_off[NB * BNODES] = N_EDGES;

    for (int i = tid; i < cnt; i += 256) {
        unsigned p = buf[i];
        int pos = atomicAdd(&cur[p & (BNODES - 1)], 1);
        pairs[beg + pos] = p >> BSHIFT;     // store plain src id, node-sorted
    }
}

// ---------------------------------------------------------------------------
// Y = feat @ W1 -> packed bf16. Thread per node, float4 row loads, W1 in LDS.
// ---------------------------------------------------------------------------
__global__ __launch_bounds__(256) void k_mm1(const float* __restrict__ feat,
                                             const float* __restrict__ W1,
                                             unsigned* __restrict__ Yu) {
    __shared__ float sW[D_IN * D_HID];  // 8 KB
    for (int i = threadIdx.x; i < D_IN * D_HID; i += 256)
        sW[i] = W1[i];
    __syncthreads();

    int n = blockIdx.x * 256 + threadIdx.x;
    if (n >= N_NODES) return;

    const float4* f4 = (const float4*)(feat + (size_t)n * D_IN);
    const float4* sW4 = (const float4*)sW;

    float4 acc[4];
#pragma unroll
    for (int q = 0; q < 4; ++q) acc[q] = make_float4(0.f, 0.f, 0.f, 0.f);

#pragma unroll 8
    for (int kq = 0; kq < 32; ++kq) {
        float4 f = f4[kq];
        int k0 = kq * 4;
#pragma unroll
        for (int jq = 0; jq < 4; ++jq) {
            float4 w0 = sW4[(k0 + 0) * 4 + jq];
            float4 w1 = sW4[(k0 + 1) * 4 + jq];
            float4 w2 = sW4[(k0 + 2) * 4 + jq];
            float4 w3 = sW4[(k0 + 3) * 4 + jq];
            acc[jq].x += f.x * w0.x + f.y * w1.x + f.z * w2.x + f.w * w3.x;
            acc[jq].y += f.x * w0.y + f.y * w1.y + f.z * w2.y + f.w * w3.y;
            acc[jq].z += f.x * w0.z + f.y * w1.z + f.z * w2.z + f.w * w3.z;
            acc[jq].w += f.x * w0.w + f.y * w1.w + f.z * w2.w + f.w * w3.w;
        }
    }
    uint4 o0, o1;
    o0.x = bf_pack(acc[0].x, acc[0].y);
    o0.y = bf_pack(acc[0].z, acc[0].w);
    o0.z = bf_pack(acc[1].x, acc[1].y);
    o0.w = bf_pack(acc[1].z, acc[1].w);
    o1.x = bf_pack(acc[2].x, acc[2].y);
    o1.y = bf_pack(acc[2].z, acc[2].w);
    o1.z = bf_pack(acc[3].x, acc[3].y);
    o1.w = bf_pack(acc[3].z, acc[3].w);
    uint4* y = (uint4*)(Yu + (size_t)n * 8);
    y[0] = o0;
    y[1] = o1;
}

// ---------------------------------------------------------------------------
// Layer-1 aggregation: 8 lanes per node, pure register accumulation over the
// node's sorted edge run (no atomics). 4 independent partial sums for MLP.
// Fused bias+ReLU -> packed bf16 H1.
// ---------------------------------------------------------------------------
__global__ __launch_bounds__(256) void k_agg1(const int* __restrict__ node_off,
                                              const unsigned* __restrict__ csr,
                                              const unsigned* __restrict__ Yu,
                                              const float* __restrict__ bias1,
                                              unsigned* __restrict__ H1u) {
    int tid = threadIdx.x;
    int g = tid >> 3;          // node slot 0..31
    int c = tid & 7;           // channel pair
    int n = blockIdx.x * 32 + g;
    if (n >= N_NODES) return;

    int beg = node_off[n], end = node_off[n + 1];
    float a0 = 0.f, a1 = 0.f, b0 = 0.f, b1v = 0.f;
    float c0 = 0.f, c1 = 0.f, d0f = 0.f, d1f = 0.f;
    int i = beg;
    for (; i + 3 < end; i += 4) {
        unsigned s0 = csr[i],     s1 = csr[i + 1];
        unsigned s2 = csr[i + 2], s3 = csr[i + 3];
        unsigned w0 = Yu[(size_t)s0 * 8 + c];
        unsigned w1 = Yu[(size_t)s1 * 8 + c];
        unsigned w2 = Yu[(size_t)s2 * 8 + c];
        unsigned w3 = Yu[(size_t)s3 * 8 + c];
        a0 += bf_lo(w0); a1 += bf_hi(w0);
        b0 += bf_lo(w1); b1v += bf_hi(w1);
        c0 += bf_lo(w2); c1 += bf_hi(w2);
        d0f += bf_lo(w3); d1f += bf_hi(w3);
    }
    for (; i < end; ++i) {
        unsigned s = csr[i];
        unsigned w = Yu[(size_t)s * 8 + c];
        a0 += bf_lo(w); a1 += bf_hi(w);
    }
    float f0 = (a0 + b0) + (c0 + d0f) + bias1[2 * c];
    float f1 = (a1 + b1v) + (c1 + d1f) + bias1[2 * c + 1];
    f0 = fmaxf(f0, 0.f);
    f1 = fmaxf(f1, 0.f);
    H1u[(size_t)n * 8 + c] = bf_pack(f0, f1);
}

// ---------------------------------------------------------------------------
// Layer-2 aggregation (register accumulation) + fused mm2 epilogue via LDS.
// ---------------------------------------------------------------------------
__global__ __launch_bounds__(256) void k_agg2(const int* __restrict__ node_off,
                                              const unsigned* __restrict__ csr,
                                              const unsigned* __restrict__ H1u,
                                              const float* __restrict__ W2,
                                              const float* __restrict__ b2,
                                              float* __restrict__ out) {
    __shared__ float sacc[32][D_HID + 1];  // 32 nodes x 16 ch, padded
    __shared__ float sW2[D_HID * D_OUT];   // 2 KB
    __shared__ float sb2[D_OUT];
    int tid = threadIdx.x;
    for (int i = tid; i < D_HID * D_OUT; i += 256) sW2[i] = W2[i];
    if (tid < D_OUT) sb2[tid] = b2[tid];

    int g = tid >> 3;
    int c = tid & 7;
    int n = blockIdx.x * 32 + g;

    float a0 = 0.f, a1 = 0.f, b0 = 0.f, b1v = 0.f;
    float c0 = 0.f, c1 = 0.f, d0f = 0.f, d1f = 0.f;
    if (n < N_NODES) {
        int beg = node_off[n], end = node_off[n + 1];
        int i = beg;
        for (; i + 3 < end; i += 4) {
            unsigned s0 = csr[i],     s1 = csr[i + 1];
            unsigned s2 = csr[i + 2], s3 = csr[i + 3];
            unsigned w0 = H1u[(size_t)s0 * 8 + c];
            unsigned w1 = H1u[(size_t)s1 * 8 + c];
            unsigned w2 = H1u[(size_t)s2 * 8 + c];
            unsigned w3 = H1u[(size_t)s3 * 8 + c];
            a0 += bf_lo(w0); a1 += bf_hi(w0);
            b0 += bf_lo(w1); b1v += bf_hi(w1);
            c0 += bf_lo(w2); c1 += bf_hi(w2);
            d0f += bf_lo(w3); d1f += bf_hi(w3);
        }
        for (; i < end; ++i) {
            unsigned s = csr[i];
            unsigned w = H1u[(size_t)s * 8 + c];
            a0 += bf_lo(w); a1 += bf_hi(w);
        }
    }
    sacc[g][2 * c]     = (a0 + b0) + (c0 + d0f);
    sacc[g][2 * c + 1] = (a1 + b1v) + (c1 + d1f);
    __syncthreads();

    // mm2: 32 nodes x 32 outputs = 1024 -> 4 per thread
    for (int t = tid; t < 32 * D_OUT; t += 256) {
        int gg = t >> 5, o = t & 31;
        int node = blockIdx.x * 32 + gg;
        if (node < N_NODES) {
            float a = sb2[o];
#pragma unroll
            for (int j = 0; j < D_HID; ++j)
                a = fmaf(sacc[gg][j], sW2[j * D_OUT + o], a);
            out[(size_t)node * D_OUT + o] = a;
        }
    }
}

// ---------------------------------------------------------------------------
extern "C" void kernel_launch(void* const* d_in, const int* in_sizes, int n_in,
                              void* d_out, int out_size, void* d_ws, size_t ws_size,
                              hipStream_t stream) {
    const float* feat = (const float*)d_in[0];
    const int*   src  = (const int*)d_in[1];
    const int*   dst  = (const int*)d_in[2];
    const float* W1   = (const float*)d_in[3];
    const float* b1   = (const float*)d_in[4];
    const float* W2   = (const float*)d_in[5];
    const float* b2   = (const float*)d_in[6];
    float* out = (float*)d_out;

    // ws layout:
    //   [0      , 6.4M )  pairs/csr (u32, 1.6M)
    //   [6.4M   , 9.6M )  Y   (bf16x16 rows, packed dwords)
    //   [9.6M   , 12.8M)  H1  (bf16x16 rows, packed dwords)
    //   [12.8M  , +8K  )  counts  (NB ints)
    //   [+8K    , +16K )  offsets (NB+1 ints)
    //   [+16K   , +24K )  cursor  (NB ints)
    //   [+24K   , +424K)  node_off (NB*64+1 ints = 100033)
    char* base = (char*)d_ws;
    unsigned* pairs    = (unsigned*)(base);
    unsigned* Yu       = (unsigned*)(base + 6400000);
    unsigned* H1u      = (unsigned*)(base + 9600000);
    int*      counts   = (int*)(base + 12800000);
    int*      offsets  = (int*)(base + 12800000 + 8192);
    int*      cursor   = (int*)(base + 12800000 + 16384);
    int*      node_off = (int*)(base + 12800000 + 24576);

    // CSR build: bucket-group then per-bucket node sort
    k_zero       <<<(NB + 255) / 256, 256, 0, stream>>>(counts);
    k_hist       <<<SBLOCKS, 256, 0, stream>>>(dst, counts);
    k_scan       <<<1, 256, 0, stream>>>(counts, offsets, cursor);
    k_sortscatter<<<SBLOCKS, 256, 0, stream>>>(src, dst, cursor, pairs);
    k_nodesort   <<<NB, 256, 0, stream>>>(offsets, pairs, node_off);

    // layer 1: project (cheap order) then gather-aggregate (fused bias+ReLU)
    k_mm1 <<<(N_NODES + 255) / 256, 256, 0, stream>>>(feat, W1, Yu);
    k_agg1<<<(N_NODES + 31) / 32, 256, 0, stream>>>(node_off, pairs, Yu, b1, H1u);

    // layer 2: gather-aggregate with fused mm2 epilogue
    k_agg2<<<(N_NODES + 31) / 32, 256, 0, stream>>>(node_off, pairs, H1u, W2, b2, out);
}